// Round 4
// baseline (272.269 us; speedup 1.0000x reference)
//
#include <hip/hip_runtime.h>

// CNF vector field + exact divergence via bilinear-form trick.
//   dx  = tanh(tanh([x,t]W1+b1)W2+b2)W3+b3, /2
//   div = 0.5 * d1^T (W2 ∘ (W1[:64]^T W3^T)) d2
// R3 post-mortem: __launch_bounds__(1024,4) => VGPR clamp 64 + scratch spills
//   (WRITE_SIZE 208MB). Reverted to plain (1024).
// R4: W2+G interleaved as float4 stream WG[j/2][u] -> 1 coalesced dwordx4 per
//   2 j's (was 4 scalar strided loads) + 1-deep register prefetch.
//   Fallback to separate arrays if ws_size < 2MB.

constexpr int HD = 512;       // hidden
constexpr int DD = 64;        // data dim
constexpr int SB = 8;         // samples per block
constexpr int NB = 2048 / SB; // 256 blocks

// ---------------- G = W2 ∘ (W1[:64]^T @ W3^T), optional (W2,G) interleave ----
// grid 512 = 64 j-tiles(8) x 8 m-tiles(64); block 512 thr.
template <bool INTER>
__global__ __launch_bounds__(512) void cnf_g_kernel(
    const float* __restrict__ W1, const float* __restrict__ W2,
    const float* __restrict__ W3, float* __restrict__ Gout)
{
    __shared__ float w1t[64 * 9];   // [i][jl], pad 9
    __shared__ float w3t[64 * 65];  // [ml][i], pad 65
    __shared__ float gt[8][64];
    __shared__ float w2t[8][64];
    const int tid = threadIdx.x;
    const int j0 = (blockIdx.x & 63) * 8;
    const int m0 = (blockIdx.x >> 6) * 64;
    {
        int i = tid >> 3, jl = tid & 7;
        w1t[i * 9 + jl] = W1[i * HD + j0 + jl];
    }
    for (int e = tid; e < 64 * 64; e += 512) {
        int ml = e >> 6, i = e & 63;
        w3t[ml * 65 + i] = W3[(m0 + ml) * DD + i];
    }
    __syncthreads();
    const int jl = tid >> 6, ml = tid & 63;
    float s = 0.f;
#pragma unroll
    for (int i = 0; i < 64; ++i)
        s += w1t[i * 9 + jl] * w3t[ml * 65 + i];
    const int j = j0 + jl, m = m0 + ml;
    const float w2 = W2[j * HD + m];
    if (!INTER) {
        Gout[j * HD + m] = w2 * s;
    } else {
        gt[jl][ml]  = w2 * s;
        w2t[jl][ml] = w2;
        __syncthreads();
        if (tid < 256) {   // (j2l<4, mll<64): write float4 rows, coalesced over m
            int j2l = tid >> 6, mll = tid & 63;
            float4 v = make_float4(w2t[2 * j2l][mll],     gt[2 * j2l][mll],
                                   w2t[2 * j2l + 1][mll], gt[2 * j2l + 1][mll]);
            reinterpret_cast<float4*>(Gout)[(size_t)(j0 / 2 + j2l) * HD + m0 + mll] = v;
        }
    }
}

// ---------------- fused MLP + divergence ----------------
// 1024 threads: u = tid&511 (unit), half = tid>>9 (j-range for layer2).
template <bool INTER>
__global__ __launch_bounds__(1024) void cnf_fused_kernel(
    const float* __restrict__ tptr, const float* __restrict__ x,
    const float* __restrict__ W1, const float* __restrict__ b1,
    const float* __restrict__ W2, const float* __restrict__ b2,
    const float* __restrict__ W3, const float* __restrict__ b3,
    const float* __restrict__ Gws, float* __restrict__ out)
{
    __shared__ float4 xsv[65 * 2];       // [i][s] sample-innermost
    __shared__ float  sbuf[8192];        // 32KB: h1v+d1v -> P partials -> opart
    __shared__ float4 h2v[HD * 2];       // [m][s]
    __shared__ float  divred[8][8];

    float4* h1v = reinterpret_cast<float4*>(sbuf);          // [0..1023]
    float4* d1v = reinterpret_cast<float4*>(sbuf + 4096);   // [0..1023]

    const int tid  = threadIdx.x;
    const int s0   = blockIdx.x * SB;
    const int u    = tid & 511;
    const int half = tid >> 9;

    // ---- phase 0: stage x rows (drop col 64, append t) ----
    {
        const float tval = tptr[0];
        for (int e = tid; e < SB * 65; e += 1024) {
            int s = e / 65, i = e % 65;
            reinterpret_cast<float*>(xsv)[i * SB + s] =
                (i == DD) ? tval : x[(s0 + s) * 65 + i];
        }
    }
    __syncthreads();

    // ---- phase 1: layer 1; thread = (unit u, 4-sample group half) ----
    {
        const float bb = b1[u];
        float2 a0 = make_float2(bb, bb), a1 = make_float2(bb, bb);
        for (int ib = 0; ib < 64; ib += 8) {
            float w[8];
#pragma unroll
            for (int q = 0; q < 8; ++q) w[q] = W1[(ib + q) * HD + u];
#pragma unroll
            for (int q = 0; q < 8; ++q) {
                float4 a = xsv[2 * (ib + q) + half];
                a0.x += a.x * w[q]; a0.y += a.y * w[q];
                a1.x += a.z * w[q]; a1.y += a.w * w[q];
            }
        }
        {
            float w = W1[64 * HD + u];
            float4 a = xsv[2 * 64 + half];
            a0.x += a.x * w; a0.y += a.y * w;
            a1.x += a.z * w; a1.y += a.w * w;
        }
        float h0 = tanhf(a0.x), h1_ = tanhf(a0.y), h2_ = tanhf(a1.x), h3 = tanhf(a1.y);
        h1v[2 * u + half] = make_float4(h0, h1_, h2_, h3);
        d1v[2 * u + half] = make_float4(1.f - h0 * h0, 1.f - h1_ * h1_,
                                        1.f - h2_ * h2_, 1.f - h3 * h3);
    }
    __syncthreads();

    // ---- phase 2: layer 2 + div matvec, j-range split across halves ----
    float2 acc[4], vac[4];
    {
        const float bb = (half == 1) ? b2[u] : 0.f;
#pragma unroll
        for (int p = 0; p < 4; ++p) {
            acc[p] = make_float2(bb, bb);
            vac[p] = make_float2(0.f, 0.f);
        }
        const int jb = half * 256;

        // one (j, w, g) update: 4 LDS broadcasts + 16 FMA
        auto upd = [&](int j, float w, float g) {
            float4 ha = h1v[2 * j], hb = h1v[2 * j + 1];
            float4 da = d1v[2 * j], db = d1v[2 * j + 1];
            acc[0].x += ha.x * w; acc[0].y += ha.y * w;
            acc[1].x += ha.z * w; acc[1].y += ha.w * w;
            acc[2].x += hb.x * w; acc[2].y += hb.y * w;
            acc[3].x += hb.z * w; acc[3].y += hb.w * w;
            vac[0].x += da.x * g; vac[0].y += da.y * g;
            vac[1].x += da.z * g; vac[1].y += da.w * g;
            vac[2].x += db.x * g; vac[2].y += db.y * g;
            vac[3].x += db.z * g; vac[3].y += db.w * g;
        };

        if (INTER) {
            const float4* WGp = reinterpret_cast<const float4*>(Gws)
                              + (size_t)(half * 128) * HD + u;
            float4 nb0 = WGp[0];
            float4 nb1 = WGp[HD];
#pragma unroll 2
            for (int j2b = 0; j2b < 128; j2b += 2) {
                float4 wg0 = nb0, wg1 = nb1;
                if (j2b + 2 < 128) {
                    nb0 = WGp[(size_t)(j2b + 2) * HD];
                    nb1 = WGp[(size_t)(j2b + 3) * HD];
                }
                const int j = jb + 2 * j2b;
                upd(j + 0, wg0.x, wg0.y);
                upd(j + 1, wg0.z, wg0.w);
                upd(j + 2, wg1.x, wg1.y);
                upd(j + 3, wg1.z, wg1.w);
            }
        } else {
            const float* W2c = W2  + (size_t)jb * HD + u;
            const float* Gc  = Gws + (size_t)jb * HD + u;
            for (int j0i = 0; j0i < 256; j0i += 8) {
                float w[8], g[8];
#pragma unroll
                for (int q = 0; q < 8; ++q) {
                    w[q] = W2c[(size_t)(j0i + q) * HD];
                    g[q] = Gc[(size_t)(j0i + q) * HD];
                }
#pragma unroll
                for (int q = 0; q < 8; ++q) upd(jb + j0i + q, w[q], g[q]);
            }
        }
    }
    __syncthreads();   // all h1v/d1v reads done -> sbuf reusable as P
    {
        float2* P = reinterpret_cast<float2*>(sbuf);   // [8][512] float2
        if (half == 0) {
#pragma unroll
            for (int p = 0; p < 4; ++p) {
                P[p * 512 + u]       = acc[p];
                P[(p + 4) * 512 + u] = vac[p];
            }
        }
        __syncthreads();
        if (half == 1) {
#pragma unroll
            for (int p = 0; p < 4; ++p) {
                float2 pa = P[p * 512 + u], pv = P[(p + 4) * 512 + u];
                acc[p].x += pa.x; acc[p].y += pa.y;
                vac[p].x += pv.x; vac[p].y += pv.y;
            }
            float h[8];
            h[0] = tanhf(acc[0].x); h[1] = tanhf(acc[0].y);
            h[2] = tanhf(acc[1].x); h[3] = tanhf(acc[1].y);
            h[4] = tanhf(acc[2].x); h[5] = tanhf(acc[2].y);
            h[6] = tanhf(acc[3].x); h[7] = tanhf(acc[3].y);
            h2v[2 * u]     = make_float4(h[0], h[1], h[2], h[3]);
            h2v[2 * u + 1] = make_float4(h[4], h[5], h[6], h[7]);
            float vt[8] = {vac[0].x, vac[0].y, vac[1].x, vac[1].y,
                           vac[2].x, vac[2].y, vac[3].x, vac[3].y};
            float dp[8];
#pragma unroll
            for (int q = 0; q < 8; ++q) dp[q] = vt[q] * (1.f - h[q] * h[q]);
#pragma unroll
            for (int q = 0; q < 8; ++q) {
                float v = dp[q];
                for (int off = 32; off > 0; off >>= 1) v += __shfl_down(v, off);
                dp[q] = v;
            }
            const int wv = (tid >> 6) & 7, lane = tid & 63;
            if (lane == 0) {
#pragma unroll
                for (int q = 0; q < 8; ++q) divred[wv][q] = dp[q];
            }
        }
    }
    __syncthreads();   // h2v + divred ready; sbuf free again (opart)
    if (tid < 8) {
        float ds = 0.f;
#pragma unroll
        for (int w = 0; w < 8; ++w) ds += divred[w][tid];
        out[(s0 + tid) * 65 + DD] = 0.5f * ds;
    }

    // ---- phase 4: layer 3; thread = (part<16, k<64), 32 m's per part ----
    {
        const int k = tid & 63, part = tid >> 6;
        float o[8];
#pragma unroll
        for (int q = 0; q < 8; ++q) o[q] = 0.f;
        const int mb = part * 32;
        for (int mm = 0; mm < 32; mm += 8) {
            float w[8];
#pragma unroll
            for (int q = 0; q < 8; ++q) w[q] = W3[(mb + mm + q) * DD + k];
#pragma unroll
            for (int q = 0; q < 8; ++q) {
                const int m = mb + mm + q;
                float4 ha = h2v[2 * m], hb = h2v[2 * m + 1];
                o[0] += ha.x * w[q]; o[1] += ha.y * w[q];
                o[2] += ha.z * w[q]; o[3] += ha.w * w[q];
                o[4] += hb.x * w[q]; o[5] += hb.y * w[q];
                o[6] += hb.z * w[q]; o[7] += hb.w * w[q];
            }
        }
#pragma unroll
        for (int q = 0; q < 8; ++q) sbuf[part * 512 + q * 64 + k] = o[q];
    }
    __syncthreads();
    if (tid < 512) {
        const int s = tid >> 6, k = tid & 63;
        float sum = b3[k];
#pragma unroll
        for (int p = 0; p < 16; ++p) sum += sbuf[p * 512 + s * 64 + k];
        out[(s0 + s) * 65 + k] = 0.5f * sum;
    }
}

extern "C" void kernel_launch(void* const* d_in, const int* in_sizes, int n_in,
                              void* d_out, int out_size, void* d_ws, size_t ws_size,
                              hipStream_t stream) {
    const float* t  = (const float*)d_in[0];
    const float* x  = (const float*)d_in[1];
    const float* W1 = (const float*)d_in[2];
    const float* b1 = (const float*)d_in[3];
    const float* W2 = (const float*)d_in[4];
    const float* b2 = (const float*)d_in[5];
    const float* W3 = (const float*)d_in[6];
    const float* b3 = (const float*)d_in[7];
    float* out = (float*)d_out;
    float* G   = (float*)d_ws;

    const bool inter = ws_size >= (size_t)HD * HD * 2 * sizeof(float);  // 2 MB
    if (inter) {
        cnf_g_kernel<true><<<512, 512, 0, stream>>>(W1, W2, W3, G);
        cnf_fused_kernel<true><<<NB, 1024, 0, stream>>>(t, x, W1, b1, W2, b2, W3, b3, G, out);
    } else {
        cnf_g_kernel<false><<<512, 512, 0, stream>>>(W1, W2, W3, G);
        cnf_fused_kernel<false><<<NB, 1024, 0, stream>>>(t, x, W1, b1, W2, b2, W3, b3, G, out);
    }
}

// Round 5
// 240.595 us; speedup vs baseline: 1.1317x; 1.1317x over previous
//
#include <hip/hip_runtime.h>

// CNF vector field + exact divergence via bilinear-form trick, MFMA edition.
//   dx  = tanh(tanh([x,t]W1+b1)W2+b2)W3+b3, /2
//   div = 0.5 * d1^T (W2 ∘ (W1[:64]^T W3^T)) d2
// Phase 2 = one 16x512 @ 512x1024 bf16 GEMM: A = [h1 (rows 0-7); d1 (rows 8-15)],
// B = [W2 | G] pre-packed in MFMA B-fragment order (bf16). fp32 accumulate.
// R3/R4 lesson: 1024-thr blocks get a hard 64-VGPR cap -> keep live set < 64.

constexpr int HD = 512;
constexpr int DD = 64;
constexpr int SB = 8;
constexpr int NB = 2048 / SB;   // 256 blocks

typedef __attribute__((ext_vector_type(8))) short bf16x8;
typedef __attribute__((ext_vector_type(4))) float f32x4;

__device__ inline unsigned short f2bf(float f) {
    union { float f; unsigned u; } v; v.f = f;
    return (unsigned short)((v.u + 0x7fffu + ((v.u >> 16) & 1u)) >> 16);
}

// ---------------- pack kernel: Bpack = bf16 fragment-ordered [W2 | G] --------
// chunk c = (mat*32 + t)*16 + kk  (mat 0=W2, 1=G; t = 16-col tile; kk = 32-k step)
// lane l: 8 bf16 = B[kk*32 + (l>>4)*8 + j][t*16 + (l&15)], j=0..7  (16 B, coalesced)
// mat 1 computes G[k][n] = W2[k][n] * sum_i W1[i][k]*W3[n][i] inline.
__global__ __launch_bounds__(64) void cnf_pack_kernel(
    const float* __restrict__ W1, const float* __restrict__ W2,
    const float* __restrict__ W3, unsigned short* __restrict__ Bpack)
{
    __shared__ float w1s[64][33];
    __shared__ float w3s[16][65];
    const int b = blockIdx.x;                 // 0..1023
    const int mat = b >> 9, t = (b >> 4) & 31, kk = b & 15;
    const int l = threadIdx.x;
    const int q = l >> 4, nl = l & 15;
    const int n = t * 16 + nl;
    unsigned short o[8];
    if (mat == 0) {
#pragma unroll
        for (int j = 0; j < 8; ++j) {
            int k = kk * 32 + q * 8 + j;
            o[j] = f2bf(W2[k * HD + n]);
        }
    } else {
        for (int e = l; e < 64 * 32; e += 64) {      // W1[:, k-range], coalesced
            int i = e >> 5, kl = e & 31;
            w1s[i][kl] = W1[i * HD + kk * 32 + kl];
        }
        for (int e = l; e < 16 * 64; e += 64) {      // W3[n-range, :], coalesced
            int nn = e >> 6, i = e & 63;
            w3s[nn][i] = W3[(t * 16 + nn) * DD + i];
        }
        __syncthreads();
#pragma unroll
        for (int j = 0; j < 8; ++j) {
            int kl = q * 8 + j;
            float m = 0.f;
#pragma unroll 8
            for (int i = 0; i < 64; ++i) m += w1s[i][kl] * w3s[nl][i];
            o[j] = f2bf(W2[(kk * 32 + kl) * HD + n] * m);
        }
    }
    uint4 pk;
    pk.x = (unsigned)o[0] | ((unsigned)o[1] << 16);
    pk.y = (unsigned)o[2] | ((unsigned)o[3] << 16);
    pk.z = (unsigned)o[4] | ((unsigned)o[5] << 16);
    pk.w = (unsigned)o[6] | ((unsigned)o[7] << 16);
    reinterpret_cast<uint4*>(Bpack)[b * 64 + l] = pk;
}

// ---------------- fused MLP + divergence ----------------
__global__ __launch_bounds__(1024) void cnf_fused_kernel(
    const float* __restrict__ tptr, const float* __restrict__ x,
    const float* __restrict__ W1, const float* __restrict__ b1,
    const float* __restrict__ b2, const float* __restrict__ W3,
    const float* __restrict__ b3, const unsigned short* __restrict__ Bpack,
    float* __restrict__ out)
{
    __shared__ float4 xsv[65 * 2];                 // [i][s] sample-innermost
    __shared__ unsigned short A_lds[16][520];      // bf16 A rows; pad->stride 1040B (16B-aligned, bank+4)
    __shared__ float4 h2v[HD * 2];                 // [m][s0-3],[m][s4-7]
    __shared__ float4 divred[8][2];

    const int tid  = threadIdx.x;
    const int s0   = blockIdx.x * SB;
    const int u    = tid & 511;
    const int half = tid >> 9;
    const int wave = tid >> 6, lane = tid & 63;

    // ---- phase 0: stage x rows (drop col 64, append t) ----
    {
        const float tval = tptr[0];
        for (int e = tid; e < SB * 65; e += 1024) {
            int s = e / 65, i = e % 65;
            reinterpret_cast<float*>(xsv)[i * SB + s] =
                (i == DD) ? tval : x[(s0 + s) * 65 + i];
        }
    }
    __syncthreads();

    // ---- phase 1: layer 1 fp32; thread = (unit u, 4-sample group half) ----
    {
        const float bb = b1[u];
        float2 a0 = make_float2(bb, bb), a1 = make_float2(bb, bb);
        for (int ib = 0; ib < 64; ib += 8) {
            float w[8];
#pragma unroll
            for (int qq = 0; qq < 8; ++qq) w[qq] = W1[(ib + qq) * HD + u];
#pragma unroll
            for (int qq = 0; qq < 8; ++qq) {
                float4 a = xsv[2 * (ib + qq) + half];
                a0.x += a.x * w[qq]; a0.y += a.y * w[qq];
                a1.x += a.z * w[qq]; a1.y += a.w * w[qq];
            }
        }
        {
            float w = W1[64 * HD + u];
            float4 a = xsv[2 * 64 + half];
            a0.x += a.x * w; a0.y += a.y * w;
            a1.x += a.z * w; a1.y += a.w * w;
        }
        float h0 = tanhf(a0.x), h1_ = tanhf(a0.y), h2_ = tanhf(a1.x), h3 = tanhf(a1.y);
        const int sb = 4 * half;
        A_lds[sb + 0][u] = f2bf(h0);
        A_lds[sb + 1][u] = f2bf(h1_);
        A_lds[sb + 2][u] = f2bf(h2_);
        A_lds[sb + 3][u] = f2bf(h3);
        A_lds[8 + sb + 0][u] = f2bf(1.f - h0 * h0);
        A_lds[8 + sb + 1][u] = f2bf(1.f - h1_ * h1_);
        A_lds[8 + sb + 2][u] = f2bf(1.f - h2_ * h2_);
        A_lds[8 + sb + 3][u] = f2bf(1.f - h3 * h3);
    }
    __syncthreads();

    // ---- phase 2: MFMA k-loop. waves 0-7: B=W2 (a2); waves 8-15: B=G (v) ----
    f32x4 cacc[4];
#pragma unroll
    for (int i = 0; i < 4; ++i) cacc[i] = (f32x4){0.f, 0.f, 0.f, 0.f};
    {
        const int mat = wave >> 3;
        const int t0  = (wave & 7) * 4;
        const unsigned short* arow = &A_lds[lane & 15][0];
        const int aoff = (lane >> 4) * 8;                       // ushorts
        const bf16x8* bp = reinterpret_cast<const bf16x8*>(Bpack)
                         + (size_t)((mat * 32 + t0) * 16) * 64 + lane;
        // tile stride = 16 chunks * 64 = 1024 frags; kk stride = 64 frags
#pragma unroll 4
        for (int kk = 0; kk < 16; ++kk) {
            bf16x8 af = *reinterpret_cast<const bf16x8*>(arow + kk * 32 + aoff);
            bf16x8 b0 = bp[kk * 64];
            bf16x8 b1f = bp[kk * 64 + 1024];
            bf16x8 b2f = bp[kk * 64 + 2048];
            bf16x8 b3f = bp[kk * 64 + 3072];
            cacc[0] = __builtin_amdgcn_mfma_f32_16x16x32_bf16(af, b0,  cacc[0], 0, 0, 0);
            cacc[1] = __builtin_amdgcn_mfma_f32_16x16x32_bf16(af, b1f, cacc[1], 0, 0, 0);
            cacc[2] = __builtin_amdgcn_mfma_f32_16x16x32_bf16(af, b2f, cacc[2], 0, 0, 0);
            cacc[3] = __builtin_amdgcn_mfma_f32_16x16x32_bf16(af, b3f, cacc[3], 0, 0, 0);
        }
    }

    // GEMM1 waves: h2 = tanh(a2 + b2) -> h2v.  C rows 0-7 live in lanes 0-31.
    if (wave < 8 && lane < 32) {
        const int q = lane >> 4;              // sample quad
#pragma unroll
        for (int i = 0; i < 4; ++i) {
            const int m = (wave * 4 + i) * 16 + (lane & 15);
            const float bb = b2[m];
            float4 hv;
            hv.x = tanhf(cacc[i][0] + bb);
            hv.y = tanhf(cacc[i][1] + bb);
            hv.z = tanhf(cacc[i][2] + bb);
            hv.w = tanhf(cacc[i][3] + bb);
            h2v[2 * m + q] = hv;
        }
    }
    __syncthreads();   // h2v ready for everyone; all A_lds reads done

    float* opart = reinterpret_cast<float*>(A_lds);   // reuse as 8x512 fp32

    if (wave >= 8) {
        // div: C rows 8-15 (= d-samples 0-7) live in lanes 32-63
        if (lane >= 32) {
            const int qq = (lane >> 4) - 2;   // sample quad
            float4 dp = make_float4(0.f, 0.f, 0.f, 0.f);
#pragma unroll
            for (int i = 0; i < 4; ++i) {
                const int m = ((wave - 8) * 4 + i) * 16 + (lane & 15);
                float4 hv = h2v[2 * m + qq];
                dp.x += cacc[i][0] * (1.f - hv.x * hv.x);
                dp.y += cacc[i][1] * (1.f - hv.y * hv.y);
                dp.z += cacc[i][2] * (1.f - hv.z * hv.z);
                dp.w += cacc[i][3] * (1.f - hv.w * hv.w);
            }
#pragma unroll
            for (int off = 8; off > 0; off >>= 1) {
                dp.x += __shfl_down(dp.x, off, 16);
                dp.y += __shfl_down(dp.y, off, 16);
                dp.z += __shfl_down(dp.z, off, 16);
                dp.w += __shfl_down(dp.w, off, 16);
            }
            if ((lane & 15) == 0) divred[wave - 8][qq] = dp;
        }
    } else {
        // phase 4: layer 3 fp32. part = wave (0..7), k = lane; 64 m's per part.
        const int k = lane, part = wave;
        float o[8];
#pragma unroll
        for (int q = 0; q < 8; ++q) o[q] = 0.f;
        const int mb = part * 64;
        for (int mm = 0; mm < 64; mm += 8) {
            float w[8];
#pragma unroll
            for (int q = 0; q < 8; ++q) w[q] = W3[(mb + mm + q) * DD + k];
#pragma unroll
            for (int q = 0; q < 8; ++q) {
                const int m = mb + mm + q;
                float4 ha = h2v[2 * m], hb = h2v[2 * m + 1];
                o[0] += ha.x * w[q]; o[1] += ha.y * w[q];
                o[2] += ha.z * w[q]; o[3] += ha.w * w[q];
                o[4] += hb.x * w[q]; o[5] += hb.y * w[q];
                o[6] += hb.z * w[q]; o[7] += hb.w * w[q];
            }
        }
#pragma unroll
        for (int q = 0; q < 8; ++q) opart[part * 512 + q * 64 + k] = o[q];
    }
    __syncthreads();

    // ---- outputs ----
    if (tid < 512) {
        const int s = tid >> 6, k = tid & 63;
        float sum = b3[k];
#pragma unroll
        for (int p = 0; p < 8; ++p) sum += opart[p * 512 + s * 64 + k];
        out[(s0 + s) * 65 + k] = 0.5f * sum;
    }
    if (tid < 8) {
        const int qq = tid >> 2, r = tid & 3;
        float ds = 0.f;
#pragma unroll
        for (int w = 0; w < 8; ++w)
            ds += reinterpret_cast<const float*>(&divred[w][qq])[r];
        out[(s0 + tid) * 65 + DD] = 0.5f * ds;
    }
}

extern "C" void kernel_launch(void* const* d_in, const int* in_sizes, int n_in,
                              void* d_out, int out_size, void* d_ws, size_t ws_size,
                              hipStream_t stream) {
    const float* t  = (const float*)d_in[0];
    const float* x  = (const float*)d_in[1];
    const float* W1 = (const float*)d_in[2];
    const float* b1 = (const float*)d_in[3];
    const float* W2 = (const float*)d_in[4];
    const float* b2 = (const float*)d_in[5];
    const float* W3 = (const float*)d_in[6];
    const float* b3 = (const float*)d_in[7];
    float* out = (float*)d_out;
    unsigned short* Bpack = (unsigned short*)d_ws;   // 2*512*512 bf16 = 1 MB

    cnf_pack_kernel<<<1024, 64, 0, stream>>>(W1, W2, W3, Bpack);
    cnf_fused_kernel<<<NB, 1024, 0, stream>>>(t, x, W1, b1, b2, W3, b3, Bpack, out);
}

// Round 6
// 102.332 us; speedup vs baseline: 2.6607x; 2.3511x over previous
//
#include <hip/hip_runtime.h>

// CNF vector field + exact divergence via bilinear-form trick, MFMA edition.
//   dx  = tanh(tanh([x,t]W1+b1)W2+b2)W3+b3, /2
//   div = 0.5 * d1^T (W2 ∘ (W1[:64]^T W3^T)) d2
// Phase 2 = 16x512 @ 512x1024 bf16 GEMM: A=[h1(8);d1(8)], B=[W2|G] packed bf16.
// R4/R5 lesson: 1024-thr blocks => hard 64-VGPR cap + catastrophic spills.
// R6: 512-thr blocks (cap >=128, R1 precedent). Wave w owns cols [w*64,w*64+64)
//     of BOTH W2 and G (8 MFMA per k-step, shared A-frag); div epilogue gets
//     h2 via intra-wave __shfl (no LDS round-trip). Fast tanh via __expf.

constexpr int HD = 512;
constexpr int DD = 64;
constexpr int SB = 8;
constexpr int NB = 2048 / SB;   // 256 blocks

typedef __attribute__((ext_vector_type(8))) short bf16x8;
typedef __attribute__((ext_vector_type(4))) float f32x4;

__device__ inline unsigned short f2bf(float f) {
    union { float f; unsigned u; } v; v.f = f;
    return (unsigned short)((v.u + 0x7fffu + ((v.u >> 16) & 1u)) >> 16);
}
__device__ inline float fast_tanh(float xx) {
    float e = __expf(2.f * xx);
    return 1.f - 2.f / (e + 1.f);
}

// ---------------- pack kernel: Bpack = bf16 fragment-ordered [W2 | G] --------
// chunk c = (mat*32 + t)*16 + kk; lane l: 8 bf16 = B[kk*32+(l>>4)*8+j][t*16+(l&15)]
// (verified R5: absmax 3.9e-3). mat 1 computes G inline.
__global__ __launch_bounds__(64) void cnf_pack_kernel(
    const float* __restrict__ W1, const float* __restrict__ W2,
    const float* __restrict__ W3, unsigned short* __restrict__ Bpack)
{
    __shared__ float w1s[64][33];
    __shared__ float w3s[16][65];
    const int b = blockIdx.x;                 // 0..1023
    const int mat = b >> 9, t = (b >> 4) & 31, kk = b & 15;
    const int l = threadIdx.x;
    const int q = l >> 4, nl = l & 15;
    const int n = t * 16 + nl;
    unsigned short o[8];
    if (mat == 0) {
#pragma unroll
        for (int j = 0; j < 8; ++j) {
            int k = kk * 32 + q * 8 + j;
            o[j] = f2bf(W2[k * HD + n]);
        }
    } else {
        for (int e = l; e < 64 * 32; e += 64) {
            int i = e >> 5, kl = e & 31;
            w1s[i][kl] = W1[i * HD + kk * 32 + kl];
        }
        for (int e = l; e < 16 * 64; e += 64) {
            int nn = e >> 6, i = e & 63;
            w3s[nn][i] = W3[(t * 16 + nn) * DD + i];
        }
        __syncthreads();
#pragma unroll
        for (int j = 0; j < 8; ++j) {
            int kl = q * 8 + j;
            float m = 0.f;
#pragma unroll 8
            for (int i = 0; i < 64; ++i) m += w1s[i][kl] * w3s[nl][i];
            o[j] = f2bf(W2[(kk * 32 + kl) * HD + n] * m);
        }
    }
    uint4 pk;
    pk.x = (unsigned)o[0] | ((unsigned)o[1] << 16);
    pk.y = (unsigned)o[2] | ((unsigned)o[3] << 16);
    pk.z = (unsigned)o[4] | ((unsigned)o[5] << 16);
    pk.w = (unsigned)o[6] | ((unsigned)o[7] << 16);
    reinterpret_cast<uint4*>(Bpack)[b * 64 + l] = pk;
}

// ---------------- fused MLP + divergence, 512 threads ----------------
__global__ __launch_bounds__(512) void cnf_fused_kernel(
    const float* __restrict__ tptr, const float* __restrict__ x,
    const float* __restrict__ W1, const float* __restrict__ b1,
    const float* __restrict__ b2v, const float* __restrict__ W3,
    const float* __restrict__ b3, const unsigned short* __restrict__ Bpack,
    float* __restrict__ out)
{
    __shared__ float4 xsv[65 * 2];             // [i][s0-3],[i][s4-7]
    __shared__ unsigned short A_lds[16][520];  // bf16 A; stride 1040B (16B-aligned)
    __shared__ float4 h2v[HD * 2];             // [m][q]
    __shared__ float4 divred[8][2];
    __shared__ float sm_b2[HD];

    const int tid  = threadIdx.x;
    const int s0   = blockIdx.x * SB;
    const int wave = tid >> 6, lane = tid & 63;

    // ---- phase 0: stage x rows (drop col 64, append t) + b2 ----
    {
        const float tval = tptr[0];
        for (int e = tid; e < SB * 65; e += 512) {
            int s = e / 65, i = e % 65;
            reinterpret_cast<float*>(xsv)[i * SB + s] =
                (i == DD) ? tval : x[(s0 + s) * 65 + i];
        }
        sm_b2[tid] = b2v[tid];
    }
    __syncthreads();

    // ---- phase 1: layer 1 fp32; thread = unit u, all 8 samples ----
    {
        const int u = tid;
        const float bb = b1[u];
        float2 a0 = {bb, bb}, a1 = {bb, bb}, a2 = {bb, bb}, a3 = {bb, bb};
        for (int ib = 0; ib < 64; ib += 8) {
            float w[8];
#pragma unroll
            for (int qq = 0; qq < 8; ++qq) w[qq] = W1[(ib + qq) * HD + u];
#pragma unroll
            for (int qq = 0; qq < 8; ++qq) {
                float4 p = xsv[2 * (ib + qq)], r = xsv[2 * (ib + qq) + 1];
                a0.x += p.x * w[qq]; a0.y += p.y * w[qq];
                a1.x += p.z * w[qq]; a1.y += p.w * w[qq];
                a2.x += r.x * w[qq]; a2.y += r.y * w[qq];
                a3.x += r.z * w[qq]; a3.y += r.w * w[qq];
            }
        }
        {
            float w = W1[64 * HD + u];
            float4 p = xsv[128], r = xsv[129];
            a0.x += p.x * w; a0.y += p.y * w;
            a1.x += p.z * w; a1.y += p.w * w;
            a2.x += r.x * w; a2.y += r.y * w;
            a3.x += r.z * w; a3.y += r.w * w;
        }
        float h[8] = {fast_tanh(a0.x), fast_tanh(a0.y), fast_tanh(a1.x), fast_tanh(a1.y),
                      fast_tanh(a2.x), fast_tanh(a2.y), fast_tanh(a3.x), fast_tanh(a3.y)};
#pragma unroll
        for (int s = 0; s < 8; ++s) {
            A_lds[s][u]     = f2bf(h[s]);
            A_lds[8 + s][u] = f2bf(1.f - h[s] * h[s]);
        }
    }
    __syncthreads();

    // ---- phase 2: MFMA. wave w: cols [w*64, w*64+64) of BOTH W2 and G ----
    f32x4 cw[4], cg[4];
#pragma unroll
    for (int i = 0; i < 4; ++i) { cw[i] = (f32x4){0,0,0,0}; cg[i] = (f32x4){0,0,0,0}; }
    {
        const unsigned short* arow = &A_lds[lane & 15][0];
        const int aoff = (lane >> 4) * 8;   // ushorts
        // frag idx for W2 tile (w*4+i), step kk: ((w*4+i)*16 + kk)*64 + lane
        const bf16x8* bw = reinterpret_cast<const bf16x8*>(Bpack)
                         + (size_t)(wave * 64) * 64 + lane;
        const bf16x8* bg = bw + 32768;      // + 32*16*64 frags
#pragma unroll 4
        for (int kk = 0; kk < 16; ++kk) {
            bf16x8 af = *reinterpret_cast<const bf16x8*>(arow + kk * 32 + aoff);
            bf16x8 w0 = bw[kk * 64],        w1f = bw[kk * 64 + 1024];
            bf16x8 w2f = bw[kk * 64 + 2048], w3f = bw[kk * 64 + 3072];
            cw[0] = __builtin_amdgcn_mfma_f32_16x16x32_bf16(af, w0,  cw[0], 0, 0, 0);
            cw[1] = __builtin_amdgcn_mfma_f32_16x16x32_bf16(af, w1f, cw[1], 0, 0, 0);
            cw[2] = __builtin_amdgcn_mfma_f32_16x16x32_bf16(af, w2f, cw[2], 0, 0, 0);
            cw[3] = __builtin_amdgcn_mfma_f32_16x16x32_bf16(af, w3f, cw[3], 0, 0, 0);
            bf16x8 g0 = bg[kk * 64],        g1f = bg[kk * 64 + 1024];
            bf16x8 g2f = bg[kk * 64 + 2048], g3f = bg[kk * 64 + 3072];
            cg[0] = __builtin_amdgcn_mfma_f32_16x16x32_bf16(af, g0,  cg[0], 0, 0, 0);
            cg[1] = __builtin_amdgcn_mfma_f32_16x16x32_bf16(af, g1f, cg[1], 0, 0, 0);
            cg[2] = __builtin_amdgcn_mfma_f32_16x16x32_bf16(af, g2f, cg[2], 0, 0, 0);
            cg[3] = __builtin_amdgcn_mfma_f32_16x16x32_bf16(af, g3f, cg[3], 0, 0, 0);
        }
    }

    // ---- epilogue: h2 (lanes 0-31 rows) + div partials (lanes 32-63 rows) ----
    {
        const int q = lane >> 4;                  // row-quad 0..3
        const int src = (lane >= 32) ? lane - 32 : lane;
        float4 dp = {0.f, 0.f, 0.f, 0.f};
#pragma unroll
        for (int i = 0; i < 4; ++i) {
            const int m = wave * 64 + i * 16 + (lane & 15);
            const float bb = sm_b2[m];
            float4 hv;
            hv.x = fast_tanh(cw[i][0] + bb);
            hv.y = fast_tanh(cw[i][1] + bb);
            hv.z = fast_tanh(cw[i][2] + bb);
            hv.w = fast_tanh(cw[i][3] + bb);
            if (lane < 32) h2v[2 * m + q] = hv;   // rows 0-7 = h-samples
            float h0 = __shfl(hv.x, src), h1s = __shfl(hv.y, src);
            float h2s = __shfl(hv.z, src), h3s = __shfl(hv.w, src);
            dp.x += cg[i][0] * (1.f - h0 * h0);
            dp.y += cg[i][1] * (1.f - h1s * h1s);
            dp.z += cg[i][2] * (1.f - h2s * h2s);
            dp.w += cg[i][3] * (1.f - h3s * h3s);
        }
        if (lane >= 32) {
#pragma unroll
            for (int off = 8; off > 0; off >>= 1) {
                dp.x += __shfl_down(dp.x, off, 16);
                dp.y += __shfl_down(dp.y, off, 16);
                dp.z += __shfl_down(dp.z, off, 16);
                dp.w += __shfl_down(dp.w, off, 16);
            }
            if ((lane & 15) == 0) divred[wave][q - 2] = dp;
        }
    }
    __syncthreads();   // h2v + divred complete; A_lds free

    float* opart = reinterpret_cast<float*>(A_lds);   // 8 x 512 fp32 (16.4KB avail)

    // ---- phase 4: layer 3 fp32; part = wave, k = lane; 64 m's per part ----
    {
        const int k = lane, part = wave;
        float o[8];
#pragma unroll
        for (int q = 0; q < 8; ++q) o[q] = 0.f;
        const int mb = part * 64;
        for (int mm = 0; mm < 64; mm += 4) {
            float w[4];
#pragma unroll
            for (int q = 0; q < 4; ++q) w[q] = W3[(mb + mm + q) * DD + k];
#pragma unroll
            for (int q = 0; q < 4; ++q) {
                const int m = mb + mm + q;
                float4 ha = h2v[2 * m], hb = h2v[2 * m + 1];
                o[0] += ha.x * w[q]; o[1] += ha.y * w[q];
                o[2] += ha.z * w[q]; o[3] += ha.w * w[q];
                o[4] += hb.x * w[q]; o[5] += hb.y * w[q];
                o[6] += hb.z * w[q]; o[7] += hb.w * w[q];
            }
        }
#pragma unroll
        for (int q = 0; q < 8; ++q) opart[part * 512 + q * 64 + k] = o[q];
    }
    __syncthreads();

    // ---- outputs ----
    {
        const int s = tid >> 6, k = tid & 63;
        float sum = b3[k];
#pragma unroll
        for (int p = 0; p < 8; ++p) sum += opart[p * 512 + s * 64 + k];
        out[(s0 + s) * 65 + k] = 0.5f * sum;
    }
    if (tid < 8) {
        const int qq = tid >> 2, r = tid & 3;
        float ds = 0.f;
#pragma unroll
        for (int w = 0; w < 8; ++w)
            ds += reinterpret_cast<const float*>(&divred[w][qq])[r];
        out[(s0 + tid) * 65 + DD] = 0.5f * ds;
    }
}

extern "C" void kernel_launch(void* const* d_in, const int* in_sizes, int n_in,
                              void* d_out, int out_size, void* d_ws, size_t ws_size,
                              hipStream_t stream) {
    const float* t  = (const float*)d_in[0];
    const float* x  = (const float*)d_in[1];
    const float* W1 = (const float*)d_in[2];
    const float* b1 = (const float*)d_in[3];
    const float* W2 = (const float*)d_in[4];
    const float* b2 = (const float*)d_in[5];
    const float* W3 = (const float*)d_in[6];
    const float* b3 = (const float*)d_in[7];
    float* out = (float*)d_out;
    unsigned short* Bpack = (unsigned short*)d_ws;   // 2*512*512 bf16 = 1 MB

    cnf_pack_kernel<<<1024, 64, 0, stream>>>(W1, W2, W3, Bpack);
    cnf_fused_kernel<<<NB, 512, 0, stream>>>(t, x, W1, b1, b2, W3, b3, Bpack, out);
}

// Round 7
// 97.810 us; speedup vs baseline: 2.7837x; 1.0462x over previous
//
#include <hip/hip_runtime.h>

// CNF vector field + exact divergence via bilinear-form trick, MFMA edition.
//   dx  = tanh(tanh([x,t]W1+b1)W2+b2)W3+b3, /2
//   div = 0.5 * d1^T (W2 ∘ (W1[:64]^T W3^T)) d2
// Phase 2 = 16x512 @ 512x1024 bf16 GEMM: A=[h1(8);d1(8)], B=[W2|G] packed bf16.
// R6 lesson: ~60us of total is harness residue (d_ws 0xAA fill = 40us + restores);
//   512-thr blocks spill-free. R7: __launch_bounds__(512,2) => 256-VGPR budget
//   (1 block/CU, grid=256), explicit ping-pong prefetch of 2-kk super-batches
//   (16 b128 in flight) to convert the L2-latency-bound k-loop to BW-bound.

constexpr int HD = 512;
constexpr int DD = 64;
constexpr int SB = 8;
constexpr int NB = 2048 / SB;   // 256 blocks

typedef __attribute__((ext_vector_type(8))) short bf16x8;
typedef __attribute__((ext_vector_type(4))) float f32x4;

__device__ inline unsigned short f2bf(float f) {
    union { float f; unsigned u; } v; v.f = f;
    return (unsigned short)((v.u + 0x7fffu + ((v.u >> 16) & 1u)) >> 16);
}
__device__ inline float fast_tanh(float xx) {
    float e = __expf(2.f * xx);
    return 1.f - 2.f / (e + 1.f);
}

// ---------------- pack kernel: Bpack = bf16 fragment-ordered [W2 | G] --------
// chunk c = (mat*32 + t)*16 + kk; lane l: 8 bf16 = B[kk*32+(l>>4)*8+j][t*16+(l&15)]
// (layout verified R5/R6: absmax 3.9e-3). mat 1 computes G inline.
__global__ __launch_bounds__(64) void cnf_pack_kernel(
    const float* __restrict__ W1, const float* __restrict__ W2,
    const float* __restrict__ W3, unsigned short* __restrict__ Bpack)
{
    __shared__ float w1s[64][33];
    __shared__ float w3s[16][65];
    const int b = blockIdx.x;                 // 0..1023
    const int mat = b >> 9, t = (b >> 4) & 31, kk = b & 15;
    const int l = threadIdx.x;
    const int q = l >> 4, nl = l & 15;
    const int n = t * 16 + nl;
    unsigned short o[8];
    if (mat == 0) {
#pragma unroll
        for (int j = 0; j < 8; ++j) {
            int k = kk * 32 + q * 8 + j;
            o[j] = f2bf(W2[k * HD + n]);
        }
    } else {
        for (int e = l; e < 64 * 32; e += 64) {
            int i = e >> 5, kl = e & 31;
            w1s[i][kl] = W1[i * HD + kk * 32 + kl];
        }
        for (int e = l; e < 16 * 64; e += 64) {
            int nn = e >> 6, i = e & 63;
            w3s[nn][i] = W3[(t * 16 + nn) * DD + i];
        }
        __syncthreads();
#pragma unroll
        for (int j = 0; j < 8; ++j) {
            int kl = q * 8 + j;
            float m = 0.f;
#pragma unroll 8
            for (int i = 0; i < 64; ++i) m += w1s[i][kl] * w3s[nl][i];
            o[j] = f2bf(W2[(kk * 32 + kl) * HD + n] * m);
        }
    }
    uint4 pk;
    pk.x = (unsigned)o[0] | ((unsigned)o[1] << 16);
    pk.y = (unsigned)o[2] | ((unsigned)o[3] << 16);
    pk.z = (unsigned)o[4] | ((unsigned)o[5] << 16);
    pk.w = (unsigned)o[6] | ((unsigned)o[7] << 16);
    reinterpret_cast<uint4*>(Bpack)[b * 64 + l] = pk;
}

// ---------------- fused MLP + divergence, 512 threads ----------------
__global__ __launch_bounds__(512, 2) void cnf_fused_kernel(
    const float* __restrict__ tptr, const float* __restrict__ x,
    const float* __restrict__ W1, const float* __restrict__ b1,
    const float* __restrict__ b2v, const float* __restrict__ W3,
    const float* __restrict__ b3, const unsigned short* __restrict__ Bpack,
    float* __restrict__ out)
{
    __shared__ float4 xsv[65 * 2];             // [i][s0-3],[i][s4-7]
    __shared__ unsigned short A_lds[16][520];  // bf16 A; stride 1040B (16B-aligned)
    __shared__ float4 h2v[HD * 2];             // [m][q]
    __shared__ float4 divred[8][2];
    __shared__ float sm_b2[HD];

    const int tid  = threadIdx.x;
    const int s0   = blockIdx.x * SB;
    const int wave = tid >> 6, lane = tid & 63;

    // ---- phase 0: stage x rows (drop col 64, append t) + b2 ----
    {
        const float tval = tptr[0];
        for (int e = tid; e < SB * 65; e += 512) {
            int s = e / 65, i = e % 65;
            reinterpret_cast<float*>(xsv)[i * SB + s] =
                (i == DD) ? tval : x[(s0 + s) * 65 + i];
        }
        sm_b2[tid] = b2v[tid];
    }
    __syncthreads();

    // ---- phase 1: layer 1 fp32; thread = unit u, all 8 samples ----
    {
        const int u = tid;
        const float bb = b1[u];
        float2 a0 = {bb, bb}, a1 = {bb, bb}, a2 = {bb, bb}, a3 = {bb, bb};
        for (int ib = 0; ib < 64; ib += 8) {
            float w[8];
#pragma unroll
            for (int qq = 0; qq < 8; ++qq) w[qq] = W1[(ib + qq) * HD + u];
#pragma unroll
            for (int qq = 0; qq < 8; ++qq) {
                float4 p = xsv[2 * (ib + qq)], r = xsv[2 * (ib + qq) + 1];
                a0.x += p.x * w[qq]; a0.y += p.y * w[qq];
                a1.x += p.z * w[qq]; a1.y += p.w * w[qq];
                a2.x += r.x * w[qq]; a2.y += r.y * w[qq];
                a3.x += r.z * w[qq]; a3.y += r.w * w[qq];
            }
        }
        {
            float w = W1[64 * HD + u];
            float4 p = xsv[128], r = xsv[129];
            a0.x += p.x * w; a0.y += p.y * w;
            a1.x += p.z * w; a1.y += p.w * w;
            a2.x += r.x * w; a2.y += r.y * w;
            a3.x += r.z * w; a3.y += r.w * w;
        }
        float h[8] = {fast_tanh(a0.x), fast_tanh(a0.y), fast_tanh(a1.x), fast_tanh(a1.y),
                      fast_tanh(a2.x), fast_tanh(a2.y), fast_tanh(a3.x), fast_tanh(a3.y)};
#pragma unroll
        for (int s = 0; s < 8; ++s) {
            A_lds[s][u]     = f2bf(h[s]);
            A_lds[8 + s][u] = f2bf(1.f - h[s] * h[s]);
        }
    }
    __syncthreads();

    // ---- phase 2: MFMA. wave w: cols [w*64, w*64+64) of BOTH W2 and G ----
    f32x4 cw[4], cg[4];
#pragma unroll
    for (int i = 0; i < 4; ++i) { cw[i] = (f32x4){0,0,0,0}; cg[i] = (f32x4){0,0,0,0}; }
    {
        const unsigned short* arow = &A_lds[lane & 15][0];
        const int aoff = (lane >> 4) * 8;   // ushorts
        const bf16x8* bw = reinterpret_cast<const bf16x8*>(Bpack)
                         + (size_t)(wave * 64) * 64 + lane;
        const bf16x8* bg = bw + 32768;      // + 32 tiles * 1024 frags

        bf16x8 pA[16], pB[16];              // ping-pong super-batches (2 kk each)
        auto loadSB = [&](bf16x8* d, int kk) {
#pragma unroll
            for (int i = 0; i < 4; ++i) {
                d[i]      = bw[kk * 64 + i * 1024];
                d[4 + i]  = bg[kk * 64 + i * 1024];
                d[8 + i]  = bw[(kk + 1) * 64 + i * 1024];
                d[12 + i] = bg[(kk + 1) * 64 + i * 1024];
            }
        };
        auto mfmaSB = [&](const bf16x8* d, int kk) {
            bf16x8 af0 = *reinterpret_cast<const bf16x8*>(arow + kk * 32 + aoff);
#pragma unroll
            for (int i = 0; i < 4; ++i)
                cw[i] = __builtin_amdgcn_mfma_f32_16x16x32_bf16(af0, d[i], cw[i], 0, 0, 0);
#pragma unroll
            for (int i = 0; i < 4; ++i)
                cg[i] = __builtin_amdgcn_mfma_f32_16x16x32_bf16(af0, d[4 + i], cg[i], 0, 0, 0);
            bf16x8 af1 = *reinterpret_cast<const bf16x8*>(arow + (kk + 1) * 32 + aoff);
#pragma unroll
            for (int i = 0; i < 4; ++i)
                cw[i] = __builtin_amdgcn_mfma_f32_16x16x32_bf16(af1, d[8 + i], cw[i], 0, 0, 0);
#pragma unroll
            for (int i = 0; i < 4; ++i)
                cg[i] = __builtin_amdgcn_mfma_f32_16x16x32_bf16(af1, d[12 + i], cg[i], 0, 0, 0);
        };

        loadSB(pA, 0);
#pragma unroll
        for (int kb = 0; kb < 8; ++kb) {
            bf16x8* cur = (kb & 1) ? pB : pA;
            bf16x8* nxt = (kb & 1) ? pA : pB;
            if (kb < 7) loadSB(nxt, (kb + 1) * 2);
            mfmaSB(cur, kb * 2);
        }
    }

    // ---- epilogue: h2 (lanes 0-31 rows) + div partials (lanes 32-63 rows) ----
    {
        const int q = lane >> 4;                  // row-quad 0..3
        const int src = (lane >= 32) ? lane - 32 : lane;
        float4 dp = {0.f, 0.f, 0.f, 0.f};
#pragma unroll
        for (int i = 0; i < 4; ++i) {
            const int m = wave * 64 + i * 16 + (lane & 15);
            const float bb = sm_b2[m];
            float4 hv;
            hv.x = fast_tanh(cw[i][0] + bb);
            hv.y = fast_tanh(cw[i][1] + bb);
            hv.z = fast_tanh(cw[i][2] + bb);
            hv.w = fast_tanh(cw[i][3] + bb);
            if (lane < 32) h2v[2 * m + q] = hv;   // rows 0-7 = h-samples
            float h0 = __shfl(hv.x, src), h1s = __shfl(hv.y, src);
            float h2s = __shfl(hv.z, src), h3s = __shfl(hv.w, src);
            dp.x += cg[i][0] * (1.f - h0 * h0);
            dp.y += cg[i][1] * (1.f - h1s * h1s);
            dp.z += cg[i][2] * (1.f - h2s * h2s);
            dp.w += cg[i][3] * (1.f - h3s * h3s);
        }
        if (lane >= 32) {
#pragma unroll
            for (int off = 8; off > 0; off >>= 1) {
                dp.x += __shfl_down(dp.x, off, 16);
                dp.y += __shfl_down(dp.y, off, 16);
                dp.z += __shfl_down(dp.z, off, 16);
                dp.w += __shfl_down(dp.w, off, 16);
            }
            if ((lane & 15) == 0) divred[wave][q - 2] = dp;
        }
    }
    __syncthreads();   // h2v + divred complete; A_lds free

    float* opart = reinterpret_cast<float*>(A_lds);   // 8 x 512 fp32

    // ---- phase 4: layer 3 fp32; part = wave, k = lane; 64 m's per part ----
    {
        const int k = lane, part = wave;
        float o[8];
#pragma unroll
        for (int q = 0; q < 8; ++q) o[q] = 0.f;
        const int mb = part * 64;
        for (int mm = 0; mm < 64; mm += 4) {
            float w[4];
#pragma unroll
            for (int q = 0; q < 4; ++q) w[q] = W3[(mb + mm + q) * DD + k];
#pragma unroll
            for (int q = 0; q < 4; ++q) {
                const int m = mb + mm + q;
                float4 ha = h2v[2 * m], hb = h2v[2 * m + 1];
                o[0] += ha.x * w[q]; o[1] += ha.y * w[q];
                o[2] += ha.z * w[q]; o[3] += ha.w * w[q];
                o[4] += hb.x * w[q]; o[5] += hb.y * w[q];
                o[6] += hb.z * w[q]; o[7] += hb.w * w[q];
            }
        }
#pragma unroll
        for (int q = 0; q < 8; ++q) opart[part * 512 + q * 64 + k] = o[q];
    }
    __syncthreads();

    // ---- outputs ----
    {
        const int s = tid >> 6, k = tid & 63;
        float sum = b3[k];
#pragma unroll
        for (int p = 0; p < 8; ++p) sum += opart[p * 512 + s * 64 + k];
        out[(s0 + s) * 65 + k] = 0.5f * sum;
    }
    if (tid < 8) {
        const int qq = tid >> 2, r = tid & 3;
        float ds = 0.f;
#pragma unroll
        for (int w = 0; w < 8; ++w)
            ds += reinterpret_cast<const float*>(&divred[w][qq])[r];
        out[(s0 + tid) * 65 + DD] = 0.5f * ds;
    }
}

extern "C" void kernel_launch(void* const* d_in, const int* in_sizes, int n_in,
                              void* d_out, int out_size, void* d_ws, size_t ws_size,
                              hipStream_t stream) {
    const float* t  = (const float*)d_in[0];
    const float* x  = (const float*)d_in[1];
    const float* W1 = (const float*)d_in[2];
    const float* b1 = (const float*)d_in[3];
    const float* W2 = (const float*)d_in[4];
    const float* b2 = (const float*)d_in[5];
    const float* W3 = (const float*)d_in[6];
    const float* b3 = (const float*)d_in[7];
    float* out = (float*)d_out;
    unsigned short* Bpack = (unsigned short*)d_ws;   // 2*512*512 bf16 = 1 MB

    cnf_pack_kernel<<<1024, 64, 0, stream>>>(W1, W2, W3, Bpack);
    cnf_fused_kernel<<<NB, 512, 0, stream>>>(t, x, W1, b1, b2, W3, b3, Bpack, out);
}